// Round 4
// baseline (181.921 us; speedup 1.0000x reference)
//
#include <hip/hip_runtime.h>
#include <math.h>

// Round 4: wave-per-strip register pipeline (R3 dataflow) with:
//  - ring buffers as arrays, trip count 35 = 7*5, #pragma unroll 5 ->
//    constant (t+k)%5 indices -> register renaming, no shift movs
//  - template<EDGE> peel: interior segments have zero y-boundary selects
//  - uniform row pointers -> scalar-base global loads (no per-lane 64b addr)
//  - NSEG=23 (SEG=23): 7360 waves ~= 90% of the 8192 wave slots
#define IMW 512
#define SEG 23
#define NSEG 23            // 23*23 = 529 >= 512
#define NSTRIP 10          // 10*52 = 520 >= 512
#define OUTW 52
#define TRIPS (SEG + 12)   // 35

__device__ __forceinline__ int reflect512(int i) {   // valid for i in [-511,1022]
    int a = i < 0 ? -i : i;
    int b = 1022 - a;
    return a < b ? a : b;
}
__device__ __forceinline__ float bperm(int a4, float v) {
    return __int_as_float(__builtin_amdgcn_ds_bpermute(a4, __float_as_int(v)));
}

template<bool EDGE>
__device__ __forceinline__ void pipe_run(
    const float* __restrict__ base0, const float* __restrict__ base1,
    const float* __restrict__ base2, float* __restrict__ outp,
    int Y0, int xr, bool inimg, bool stlane, int l4, int aL4, int aR4)
{
    const float K0 = 0.054488684549643f, K1 = 0.244201342003233f, K2 = 0.402619946931554f;

    // rings: slot for a row produced at trip t is t%5 (reads use (t+k)%5, k>=0)
    float hb[5], hx[5], hy[5], mg[5], cm[5];
    int   ax[5];
    #pragma unroll
    for (int i = 0; i < 5; ++i) { hb[i]=0.f; hx[i]=0.f; hy[i]=0.f; mg[i]=0.f; cm[i]=0.f; ax[i]=0; }

    // prefetch gray inputs for row v = Y0-6
    int r0i = Y0 - 6;
    if (EDGE) r0i = reflect512(r0i);
    float p0 = (base0 + (size_t)r0i * IMW)[xr];
    float p1 = (base1 + (size_t)r0i * IMW)[xr];
    float p2 = (base2 + (size_t)r0i * IMW)[xr];

    #pragma unroll 5
    for (int t = 0; t < TRIPS; ++t) {
        const int v = Y0 - 6 + t;

        // ---- gray row v (channel-reversed) + prefetch row v+1 (uniform base)
        float gray = 0.299f * p2 + 0.587f * p1 + 0.114f * p0;
        int rn = v + 1;
        if (EDGE) rn = reflect512(rn);
        const float* r0 = base0 + (size_t)rn * IMW;
        const float* r1 = base1 + (size_t)rn * IMW;
        const float* r2 = base2 + (size_t)rn * IMW;
        p0 = r0[xr]; p1 = r1[xr]; p2 = r2[xr];

        // ---- h-blur row v -> hb[t%5]
        float gl1 = bperm(l4 - 4, gray), gl2 = bperm(l4 - 8, gray);
        float gr1 = bperm(l4 + 4, gray), gr2 = bperm(l4 + 8, gray);
        hb[t % 5] = K0 * (gl2 + gr2) + K1 * (gl1 + gr1) + K2 * gray;

        // ---- v-blur row v-2 (rows v-4..v = slots (t+1),(t+2),(t+3),(t+4),(t))
        float blur = K0 * (hb[(t + 1) % 5] + hb[t % 5])
                   + K1 * (hb[(t + 2) % 5] + hb[(t + 4) % 5])
                   + K2 * hb[(t + 3) % 5];

        // ---- sobel h-passes row v-2 -> hx/hy[t%5] (x edge-clamped addresses)
        float bl = bperm(aL4, blur), br = bperm(aR4, blur);
        hx[t % 5] = br - bl;
        hy[t % 5] = bl + 2.f * blur + br;

        // ---- sobel v + mag + axis at row g = v-3
        // hx rows g-1,g,g+1 = slots (t+3),(t+4),(t)
        float hxa, hxc, hya, hyc;
        if (EDGE) {
            const int g = v - 3;
            hxa = (g == 0)   ? hx[(t + 4) % 5] : hx[(t + 3) % 5];
            hya = (g == 0)   ? hy[(t + 4) % 5] : hy[(t + 3) % 5];
            hxc = (g == 511) ? hx[(t + 4) % 5] : hx[t % 5];
            hyc = (g == 511) ? hy[(t + 4) % 5] : hy[t % 5];
        } else {
            hxa = hx[(t + 3) % 5]; hya = hy[(t + 3) % 5];
            hxc = hx[t % 5];       hyc = hy[t % 5];
        }
        float gxv = (hxa + 2.f * hx[(t + 4) % 5] + hxc) * 0.125f;
        float gyv = (hyc - hya) * 0.125f;
        float mag = sqrtf(gxv * gxv + gyv * gyv + 1e-6f);
        float axm = fabsf(gxv), aym = fabsf(gyv);
        int axis;
        if (aym <= 0.41421356237309515f * axm)      axis = 0;  // (0,+-1)
        else if (aym >= 2.4142135623730951f * axm)  axis = 2;  // (+-1,0)
        else axis = ((gxv >= 0.f) == (gyv >= 0.f)) ? 1 : 3;    // diagonals
        mg[t % 5] = inimg ? mag : 0.f;
        ax[t % 5] = axis;

        // ---- NMS row m = v-4: magc=slot(t+4), magp=slot(t), magm=slot(t+3)
        const int m = v - 4;
        float magc = mg[(t + 4) % 5];
        float magp, magm;
        if (EDGE) {
            magp = (m >= 511) ? 0.f : mg[t % 5];
            magm = (m <= 0)   ? 0.f : mg[(t + 3) % 5];
        } else {
            magp = mg[t % 5];
            magm = mg[(t + 3) % 5];
        }
        float gcp = bperm(l4 + 4, magc), gcm = bperm(l4 - 4, magc);
        float gpp = bperm(l4 + 4, magp), gpm = bperm(l4 - 4, magp);
        float gmm = bperm(l4 - 4, magm), gmp = bperm(l4 + 4, magm);
        int d = ax[(t + 4) % 5];
        float mp = (d == 0) ? gcp : (d == 1) ? gpp : (d == 2) ? magp : gpm;
        float mn = (d == 0) ? gcm : (d == 1) ? gmm : (d == 2) ? magm : gmp;
        bool keep = fminf(magc - mp, magc - mn) > 0.f;
        if (EDGE) keep = keep && (m >= 0) && (m <= 511);
        float msk = keep ? magc : 0.f;   // mg already zeroed at x-OOB lanes

        // ---- horizontal 5-max -> cm[t%5] (row m)
        float s1 = fmaxf(bperm(l4 - 4, msk), bperm(l4 + 4, msk));
        float s2 = fmaxf(bperm(l4 - 8, msk), bperm(l4 + 8, msk));
        cm[t % 5] = fmaxf(fmaxf(s1, s2), msk);

        // ---- vertical 5-max -> out row y = v-6 (cm rows y-2..y+2 =
        //      slots (t+1),(t+2),(t+3),(t+4),(t))
        if (t >= 12) {
            const int y = v - 6;
            float c0 = cm[(t + 1) % 5], c1 = cm[(t + 2) % 5];
            float c2 = cm[(t + 3) % 5];
            float c3 = cm[(t + 4) % 5], c4 = cm[t % 5];
            if (EDGE) {
                if (y < 2)   { c0 = 0.f; if (y < 1)   c1 = 0.f; }
                if (y > 509) { c4 = 0.f; if (y > 510) c3 = 0.f; }
            }
            float val = fmaxf(fmaxf(fmaxf(c0, c1), fmaxf(c2, c3)), c4);
            if ((!EDGE || y < 512) && stlane)
                outp[(size_t)y * IMW] = val;
        }
    }
}

__global__ __launch_bounds__(256)
void canny_pipe(const float* __restrict__ x, float* __restrict__ out) {
    const int lane  = threadIdx.x & 63;
    const int unit  = blockIdx.x * 4 + (threadIdx.x >> 6);
    const int img   = unit / (NSTRIP * NSEG);
    const int rem   = unit - img * (NSTRIP * NSEG);
    const int strip = rem / NSEG;
    const int seg   = rem - strip * NSEG;
    const int Y0 = seg * SEG;
    const int x0 = strip * OUTW - 6;
    const int xv = x0 + lane;
    const int xr = reflect512(xv);
    const bool inimg  = (xv >= 0) && (xv < IMW);
    const bool stlane = (lane >= 6) && (lane < 58) && (xv < IMW);
    const int l4  = lane << 2;
    const int aL4 = (min(max(xv - 1, 0), 511) - x0) << 2;
    const int aR4 = (min(max(xv + 1, 0), 511) - x0) << 2;

    const float* base = x + (size_t)img * 3 * IMW * IMW;
    const float* b0 = base;
    const float* b1 = base + (size_t)IMW * IMW;
    const float* b2 = base + (size_t)2 * IMW * IMW;
    float* outp = out + (size_t)img * IMW * IMW + xv;

    if (seg >= 1 && seg <= 20)
        pipe_run<false>(b0, b1, b2, outp, Y0, xr, inimg, stlane, l4, aL4, aR4);
    else
        pipe_run<true >(b0, b1, b2, outp, Y0, xr, inimg, stlane, l4, aL4, aR4);
}

extern "C" void kernel_launch(void* const* d_in, const int* in_sizes, int n_in,
                              void* d_out, int out_size, void* d_ws, size_t ws_size,
                              hipStream_t stream) {
    const float* x = (const float*)d_in[0];
    float* out = (float*)d_out;
    const int units = 32 * NSTRIP * NSEG;   // 7360 waves
    dim3 grid(units / 4);                   // 1840 blocks, 4 waves each
    canny_pipe<<<grid, 256, 0, stream>>>(x, out);
}

// Round 5
// 175.699 us; speedup vs baseline: 1.0354x; 1.0354x over previous
//
#include <hip/hip_runtime.h>
#include <math.h>

// Round 5: wave-per-strip register pipeline, 2 columns per lane ("pairs").
// 128-wide strip per wave (116 outputs), e=even col, o=odd col per lane.
// Parity-preserving x-reflect => all cross-lane traffic is 4 gathers/stage.
// Ring arrays indexed by fully-unrolled j in nested loop -> constant %5
// indices -> no PromoteAlloca-to-LDS (R4's failure mode).
#define IMW 512
#define SEG 23
#define NSEG 23            // last seg shifted to Y0=489 (overlap, no waste)
#define NSTRIP 5           // last strip shifted to x0=396 (overlap, no waste)
#define OUTW 116
#define ITERS 7            // 7*5 = 35 = SEG+12 trips

__device__ __forceinline__ int reflect512(int i) {   // valid for [-511,1022]
    int a = i < 0 ? -i : i;
    int b = 1022 - a;
    return a < b ? a : b;
}
__device__ __forceinline__ float bperm(int a4, float v) {
    return __int_as_float(__builtin_amdgcn_ds_bpermute(a4, __float_as_int(v)));
}

template<bool XE, bool YE>
__device__ __forceinline__ void pipe_run(
    const float* __restrict__ c0p, const float* __restrict__ c1p,
    const float* __restrict__ c2p, float* __restrict__ outp,
    int Y0, int cb, bool inimgE, bool inimgO, bool stl,
    int lm4, int lp4, int srcE4, int srcO4, bool clampL, bool clampR)
{
    const float K0 = 0.054488684549643f, K1 = 0.244201342003233f, K2 = 0.402619946931554f;

    float hbE[5],hbO[5],hxE[5],hxO[5],hyE[5],hyO[5],mgE[5],mgO[5],cmE[5],cmO[5];
    int axE[5], axO[5];
    #pragma unroll
    for (int i = 0; i < 5; ++i) {
        hbE[i]=0.f;hbO[i]=0.f;hxE[i]=0.f;hxO[i]=0.f;hyE[i]=0.f;hyO[i]=0.f;
        mgE[i]=0.f;mgO[i]=0.f;cmE[i]=0.f;cmO[i]=0.f;axE[i]=0;axO[i]=0;
    }

    // prefetch gray inputs for row v = Y0-6 (interior segs: Y0-6 >= 17, in range)
    int r0 = Y0 - 6;
    if (YE) r0 = reflect512(r0);
    float2 p0 = *(const float2*)(c0p + (size_t)r0 * IMW + cb);
    float2 p1 = *(const float2*)(c1p + (size_t)r0 * IMW + cb);
    float2 p2 = *(const float2*)(c2p + (size_t)r0 * IMW + cb);

    for (int it = 0; it < ITERS; ++it) {
        #pragma unroll
        for (int j = 0; j < 5; ++j) {
            const int t = it * 5 + j;
            const int v = Y0 - 6 + t;

            // ---- gray row v (channel-reversed) + prefetch next row
            float gE = 0.299f * p2.x + 0.587f * p1.x + 0.114f * p0.x;
            float gO = 0.299f * p2.y + 0.587f * p1.y + 0.114f * p0.y;
            int rn = v + 1;
            rn = YE ? reflect512(rn) : min(rn, 511);   // avoid OOB prefetch row 512
            const float* q0 = c0p + (size_t)rn * IMW;
            const float* q1 = c1p + (size_t)rn * IMW;
            const float* q2 = c2p + (size_t)rn * IMW;
            p0 = *(const float2*)(q0 + cb);
            p1 = *(const float2*)(q1 + cb);
            p2 = *(const float2*)(q2 + cb);

            // ---- x-reflect fixup (edge strips only; identity elsewhere)
            if (XE) { gE = bperm(srcE4, gE); gO = bperm(srcO4, gO); }

            // ---- h-blur: taps ce-2..ce+2 / co-2..co+2
            float eL = bperm(lm4, gE), eR = bperm(lp4, gE);
            float oL = bperm(lm4, gO), oR = bperm(lp4, gO);
            hbE[j] = K0 * (eL + eR) + K1 * (oL + gO) + K2 * gE;
            hbO[j] = K0 * (oL + oR) + K1 * (gE + eR) + K2 * gO;

            // ---- v-blur row v-2 (rows v-4..v = slots j+1,j+2,j+3,j+4,j)
            float bE = K0 * (hbE[(j+1)%5] + hbE[j]) + K1 * (hbE[(j+2)%5] + hbE[(j+4)%5]) + K2 * hbE[(j+3)%5];
            float bO = K0 * (hbO[(j+1)%5] + hbO[j]) + K1 * (hbO[(j+2)%5] + hbO[(j+4)%5]) + K2 * hbO[(j+3)%5];

            // ---- sobel h-passes row v-2 (x edge-clamp on edge strips)
            float oLb = bperm(lm4, bO);
            float eRb = bperm(lp4, bE);
            float nblE = XE ? (clampL ? bE : oLb) : oLb;   // blur[ce-1]
            float nbrO = XE ? (clampR ? bO : eRb) : eRb;   // blur[co+1]
            hxE[j] = bO - nblE;
            hyE[j] = nblE + 2.f * bE + bO;
            hxO[j] = nbrO - bE;
            hyO[j] = bE + 2.f * bO + nbrO;

            // ---- sobel v + mag + axis at row g = v-3 (rows g-1,g,g+1 = j+3,j+4,j)
            const int g = v - 3;
            float hxaE, hxcE, hyaE, hycE, hxaO, hxcO, hyaO, hycO;
            if (YE) {
                hxaE = (g == 0)   ? hxE[(j+4)%5] : hxE[(j+3)%5];
                hyaE = (g == 0)   ? hyE[(j+4)%5] : hyE[(j+3)%5];
                hxcE = (g == 511) ? hxE[(j+4)%5] : hxE[j];
                hycE = (g == 511) ? hyE[(j+4)%5] : hyE[j];
                hxaO = (g == 0)   ? hxO[(j+4)%5] : hxO[(j+3)%5];
                hyaO = (g == 0)   ? hyO[(j+4)%5] : hyO[(j+3)%5];
                hxcO = (g == 511) ? hxO[(j+4)%5] : hxO[j];
                hycO = (g == 511) ? hyO[(j+4)%5] : hyO[j];
            } else {
                hxaE = hxE[(j+3)%5]; hyaE = hyE[(j+3)%5]; hxcE = hxE[j]; hycE = hyE[j];
                hxaO = hxO[(j+3)%5]; hyaO = hyO[(j+3)%5]; hxcO = hxO[j]; hycO = hyO[j];
            }
            float gxE = (hxaE + 2.f * hxE[(j+4)%5] + hxcE) * 0.125f;
            float gyE = (hycE - hyaE) * 0.125f;
            float gxO = (hxaO + 2.f * hxO[(j+4)%5] + hxcO) * 0.125f;
            float gyO = (hycO - hyaO) * 0.125f;
            float magE = sqrtf(gxE * gxE + gyE * gyE + 1e-6f);
            float magO = sqrtf(gxO * gxO + gyO * gyO + 1e-6f);
            {
                float axm = fabsf(gxE), aym = fabsf(gyE);
                axE[j] = (aym <= 0.41421356237309515f * axm) ? 0
                       : (aym >= 2.4142135623730951f  * axm) ? 2
                       : (((gxE >= 0.f) == (gyE >= 0.f)) ? 1 : 3);
            }
            {
                float axm = fabsf(gxO), aym = fabsf(gyO);
                axO[j] = (aym <= 0.41421356237309515f * axm) ? 0
                       : (aym >= 2.4142135623730951f  * axm) ? 2
                       : (((gxO >= 0.f) == (gyO >= 0.f)) ? 1 : 3);
            }
            mgE[j] = inimgE ? magE : 0.f;
            mgO[j] = inimgO ? magO : 0.f;

            // ---- NMS row m = v-4 (rows m-1,m,m+1 = slots j+3, j+4, j)
            const int m = v - 4;
            float magcE = mgE[(j+4)%5], magcO = mgO[(j+4)%5];
            float magpE = mgE[j],       magpO = mgO[j];
            float magmE = mgE[(j+3)%5], magmO = mgO[(j+3)%5];
            if (YE) {
                if (m >= 511) { magpE = 0.f; magpO = 0.f; }
                if (m <= 0)   { magmE = 0.f; magmO = 0.f; }
            }
            float oLc = bperm(lm4, magcO), eRc = bperm(lp4, magcE);
            float oLp = bperm(lm4, magpO), eRp = bperm(lp4, magpE);
            float oLm = bperm(lm4, magmO), eRm = bperm(lp4, magmE);
            int dE = axE[(j+4)%5], dO = axO[(j+4)%5];
            float mpE = (dE == 0) ? magcO : (dE == 1) ? magpO : (dE == 2) ? magpE : oLp;
            float mnE = (dE == 0) ? oLc   : (dE == 1) ? oLm   : (dE == 2) ? magmE : magmO;
            float mpO = (dO == 0) ? eRc   : (dO == 1) ? eRp   : (dO == 2) ? magpO : magpE;
            float mnO = (dO == 0) ? magcE : (dO == 1) ? magmE : (dO == 2) ? magmO : eRm;
            float mskE = (fminf(magcE - mpE, magcE - mnE) > 0.f) ? magcE : 0.f;
            float mskO = (fminf(magcO - mpO, magcO - mnO) > 0.f) ? magcO : 0.f;

            // ---- horizontal 5-max row m
            float eLk = bperm(lm4, mskE), eRk = bperm(lp4, mskE);
            float oLk = bperm(lm4, mskO), oRk = bperm(lp4, mskO);
            float c4 = fmaxf(fmaxf(oLk, mskE), fmaxf(mskO, eRk));
            cmE[j] = fmaxf(c4, eLk);
            cmO[j] = fmaxf(c4, oRk);

            // ---- vertical 5-max -> out row y = v-6 (rows y-2..y+2 = j+1..j+4,j)
            if (t >= 12) {
                const int y = v - 6;
                float e0 = cmE[(j+1)%5], e1 = cmE[(j+2)%5], e2 = cmE[(j+3)%5];
                float e3 = cmE[(j+4)%5], e4 = cmE[j];
                float o0 = cmO[(j+1)%5], o1 = cmO[(j+2)%5], o2 = cmO[(j+3)%5];
                float o3 = cmO[(j+4)%5], o4 = cmO[j];
                if (YE) {
                    if (y < 2)   { e0 = 0.f; o0 = 0.f; if (y < 1)   { e1 = 0.f; o1 = 0.f; } }
                    if (y > 509) { e4 = 0.f; o4 = 0.f; if (y > 510) { e3 = 0.f; o3 = 0.f; } }
                }
                float2 val;
                val.x = fmaxf(fmaxf(fmaxf(e0, e1), fmaxf(e2, e3)), e4);
                val.y = fmaxf(fmaxf(fmaxf(o0, o1), fmaxf(o2, o3)), o4);
                if (stl) *(float2*)(outp + (size_t)y * IMW) = val;
            }
        }
    }
}

__global__ __launch_bounds__(256)
void canny_pipe(const float* __restrict__ x, float* __restrict__ out) {
    const int lane  = threadIdx.x & 63;
    const int unit  = blockIdx.x * 4 + (threadIdx.x >> 6);
    const int img   = unit / (NSTRIP * NSEG);
    const int rem   = unit - img * (NSTRIP * NSEG);
    const int strip = rem / NSEG;
    const int seg   = rem - strip * NSEG;

    int Y0 = seg * SEG;       if (seg == NSEG - 1)    Y0 = 512 - SEG;   // 489
    int Xs = strip * OUTW;    if (strip == NSTRIP - 1) Xs = 512 - OUTW; // 396
    const int X0 = Xs - 6;
    const int ce = X0 + 2 * lane, co = ce + 1;
    const int cb = min(max(ce, 0), 510);               // clamped even load col
    const bool inimgE = (unsigned)ce < 512u;
    const bool inimgO = (unsigned)co < 512u;
    const bool stl = (lane >= 3) && (lane <= 60);
    const int lm4 = (lane - 1) << 2, lp4 = (lane + 1) << 2;
    // x-reflect source lanes (parity-preserving; clamp keeps don't-care lanes safe)
    const int srcE4 = ((reflect512(min(max(ce, -2), 512)) - X0) >> 1) << 2;
    const int srcO4 = ((reflect512(min(max(co, -1), 513)) - X0 - 1) >> 1) << 2;
    const bool clampL = (ce == 0), clampR = (co == 511);

    const float* base = x + (size_t)img * 3 * IMW * IMW;
    const float* c0p = base;
    const float* c1p = base + (size_t)IMW * IMW;
    const float* c2p = base + (size_t)2 * IMW * IMW;
    float* outp = out + (size_t)img * IMW * IMW + ce;

    const bool xe = (strip == 0) || (strip == NSTRIP - 1);
    const bool ye = (seg == 0) || (seg == NSEG - 1);
    if (xe) {
        if (ye) pipe_run<true , true >(c0p,c1p,c2p,outp,Y0,cb,inimgE,inimgO,stl,lm4,lp4,srcE4,srcO4,clampL,clampR);
        else    pipe_run<true , false>(c0p,c1p,c2p,outp,Y0,cb,inimgE,inimgO,stl,lm4,lp4,srcE4,srcO4,clampL,clampR);
    } else {
        if (ye) pipe_run<false, true >(c0p,c1p,c2p,outp,Y0,cb,inimgE,inimgO,stl,lm4,lp4,srcE4,srcO4,clampL,clampR);
        else    pipe_run<false, false>(c0p,c1p,c2p,outp,Y0,cb,inimgE,inimgO,stl,lm4,lp4,srcE4,srcO4,clampL,clampR);
    }
}

extern "C" void kernel_launch(void* const* d_in, const int* in_sizes, int n_in,
                              void* d_out, int out_size, void* d_ws, size_t ws_size,
                              hipStream_t stream) {
    const float* x = (const float*)d_in[0];
    float* out = (float*)d_out;
    const int units = 32 * NSTRIP * NSEG;   // 3680 waves
    dim3 grid(units / 4);                   // 920 blocks, 4 waves each
    canny_pipe<<<grid, 256, 0, stream>>>(x, out);
}